// Round 10
// baseline (355.749 us; speedup 1.0000x reference)
//
#include <hip/hip_runtime.h>

#define B_ 64
#define H_ 32
#define DN 512
#define DR 64
#define BS 128
#define TK 32
#define MAXKV 4096
#define ROWQ 584              // Q LDS row stride in f16 (584*2B: 2-way banks max)
#define LOG2E 1.44269504088896340736f
#define SCALE_ (1.0f/24.0f)   // 1/sqrt(576)
#define NEG_INF -1e30f

typedef float    f32x4 __attribute__((ext_vector_type(4)));
typedef _Float16 f16x4 __attribute__((ext_vector_type(4)));
typedef _Float16 f16x2 __attribute__((ext_vector_type(2)));

#define MFMA16 __builtin_amdgcn_mfma_f32_16x16x16f16

__device__ __forceinline__ f16x4 cvt4(f32x4 a) {
  f16x2 lo = __builtin_bit_cast(f16x2, __builtin_amdgcn_cvt_pkrtz(a[0], a[1]));
  f16x2 hi = __builtin_bit_cast(f16x2, __builtin_amdgcn_cvt_pkrtz(a[2], a[3]));
  f16x4 r; r[0] = lo[0]; r[1] = lo[1]; r[2] = hi[0]; r[3] = hi[1];
  return r;
}

// Kernel 1: per (b, chunk) flash-decode partial. NO K/V LDS staging:
// QK^T reads K rows straight from global (coalesced, streams HBM->L2);
// PV re-reads V columns from global (L2-hot: same 82 KB tile this block
// just streamed). Q lives in LDS (f16). ~41 KB LDS, 2 barriers/tile,
// occupancy-driven latency hiding (2-3 blocks/CU).
__global__ __launch_bounds__(256, 2) void mla_chunk(
    const float* __restrict__ qn, const float* __restrict__ qr,
    const float* __restrict__ kvn, const float* __restrict__ kvr,
    const int* __restrict__ btab, const int* __restrict__ kseq,
    _Float16* __restrict__ po, float* __restrict__ ml,
    const int nc, const int chunk)
{
  const int bc = blockIdx.x;
  const int b = bc / nc, c = bc - b * nc;
  const int klen = kseq[b];
  const int kbase = c * chunk;
  if (kbase >= klen) return;
  const int nvalid = min(chunk, klen - kbase);
  const int nsb = (nvalid + TK - 1) / TK;

  const int tid = threadIdx.x;
  const int w = tid >> 6, l = tid & 63, l15 = l & 15, lg = l >> 4;
  const int kd = lg * 4;
  const int wk = w >> 1, wh = w & 1;     // QK roles: key-half, head-half
  const int hw = w >> 1, dv = w & 1;     // PV roles: head-half, dim-half

  __shared__ _Float16 Qlds[H_][ROWQ];    // 37,376 B: Q nope+rope, f16
  __shared__ _Float16 Plds[H_][40];      //  2,560 B
  __shared__ float m_tab[2][H_], l_tab[2][H_];
  __shared__ float Mrun[2][H_], Lrun[2][H_];

  if (tid < H_) { Mrun[0][tid] = NEG_INF; Lrun[0][tid] = 0.f; }

  // ---- stage Q (f32 global -> f16 LDS), once per block ----
  {
    const int h = tid >> 3, seg = tid & 7;         // 8 threads per head row
    const float* qn_ = qn + ((size_t)b * H_ + h) * DN;
    const float* qr_ = qr + ((size_t)b * H_ + h) * DR;
    #pragma unroll
    for (int i = 0; i < 18; ++i) {
      const int dd = seg * 72 + i * 4;
      f32x4 q4 = (dd < DN) ? *(const f32x4*)(qn_ + dd)
                           : *(const f32x4*)(qr_ + (dd - DN));
      *(f16x4*)&Qlds[h][dd] = cvt4(q4);
    }
  }

  f32x4 acc[16];
  #pragma unroll
  for (int i = 0; i < 16; ++i) acc[i] = (f32x4){0.f, 0.f, 0.f, 0.f};

  __syncthreads();   // Qlds ready

  for (int t = 0; t < nsb; ++t) {
    const int cur = t & 1, nxt = cur ^ 1;
    const int kb = kbase + t * TK;
    const size_t br = (size_t)btab[b * 32 + (kb >> 7)] * BS + (kb & (BS - 1));

    // ---- QK^T: A = K rows from GLOBAL (coalesced), B = Q from LDS ----
    const float* kn_ = kvn + (br + wk * 16 + l15) * DN + kd;
    const float* kr_ = kvr + (br + wk * 16 + l15) * DR + kd;
    const _Float16* qrow = &Qlds[wh * 16 + l15][0];
    f32x4 sA = {0.f,0.f,0.f,0.f}, sB = {0.f,0.f,0.f,0.f};
    #pragma unroll
    for (int m = 0; m < 32; m += 2) {
      f32x4 k0 = *(const f32x4*)(kn_ + m * 16);
      f32x4 k1 = *(const f32x4*)(kn_ + (m + 1) * 16);
      f16x4 q0 = *(const f16x4*)(qrow + m * 16 + kd);
      f16x4 q1 = *(const f16x4*)(qrow + (m + 1) * 16 + kd);
      sA = MFMA16(cvt4(k0), q0, sA, 0, 0, 0);
      sB = MFMA16(cvt4(k1), q1, sB, 0, 0, 0);
    }
    #pragma unroll
    for (int m = 0; m < 4; m += 2) {
      f32x4 k0 = *(const f32x4*)(kr_ + m * 16);
      f32x4 k1 = *(const f32x4*)(kr_ + (m + 1) * 16);
      f16x4 q0 = *(const f16x4*)(qrow + DN + m * 16 + kd);
      f16x4 q1 = *(const f16x4*)(qrow + DN + (m + 1) * 16 + kd);
      sA = MFMA16(cvt4(k0), q0, sA, 0, 0, 0);
      sB = MFMA16(cvt4(k1), q1, sB, 0, 0, 0);
    }

    // D: row(key) = wk*16 + kd + r, col(head) = wh*16 + l15. Scale+mask+max.
    float v0[4]; float mx = NEG_INF;
    #pragma unroll
    for (int r = 0; r < 4; ++r) {
      const bool ok = (kb + wk * 16 + kd + r) < klen;
      v0[r] = ok ? (sA[r] + sB[r]) * SCALE_ : NEG_INF;
      mx = fmaxf(mx, v0[r]);
    }
    mx = fmaxf(mx, __shfl_xor(mx, 16));
    mx = fmaxf(mx, __shfl_xor(mx, 32));
    if (lg == 0) m_tab[wk][wh * 16 + l15] = mx;
    __syncthreads();                            // bar1

    // ---- softmax: redundant per-lane max-combine ----
    const int hC = wh * 16 + l15;
    const float moC = Mrun[cur][hC];
    const float mnC = fmaxf(fmaxf(m_tab[0][hC], m_tab[1][hC]), moC);
    float p0[4], ls = 0.f;
    #pragma unroll
    for (int r = 0; r < 4; ++r) { p0[r] = exp2f((v0[r] - mnC) * LOG2E); ls += p0[r]; }
    ls += __shfl_xor(ls, 16); ls += __shfl_xor(ls, 32);
    if (lg == 0) l_tab[wk][hC] = ls;
    f16x4 pk;
    #pragma unroll
    for (int r = 0; r < 4; ++r) pk[r] = (_Float16)p0[r];
    *(f16x4*)&Plds[hC][wk * 16 + kd] = pk;
    // rescale acc: fact recomputed per PV-head redundantly
    #pragma unroll
    for (int r = 0; r < 4; ++r) {
      const int h = hw * 16 + kd + r;
      const float mo = Mrun[cur][h];
      const float mn = fmaxf(fmaxf(m_tab[0][h], m_tab[1][h]), mo);
      const float f = exp2f((mo - mn) * LOG2E);
      #pragma unroll
      for (int dt = 0; dt < 16; ++dt) acc[dt][r] *= f;
    }
    if (tid < H_) {                            // Mrun ping-pong update
      const float mo = Mrun[cur][tid];
      Mrun[nxt][tid] = fmaxf(fmaxf(m_tab[0][tid], m_tab[1][tid]), mo);
    }
    __syncthreads();                            // bar2: P/l_tab/Mrun visible

    if (tid < H_) {                            // Lrun ping-pong update
      const float mo = Mrun[cur][tid], mn = Mrun[nxt][tid];
      const float f = exp2f((mo - mn) * LOG2E);
      Lrun[nxt][tid] = Lrun[cur][tid] * f + l_tab[0][tid] + l_tab[1][tid];
    }

    // ---- PV: A = P from LDS, B = V columns from GLOBAL (L2-hot) ----
    {
      f16x4 pa0 = *(const f16x4*)&Plds[hw * 16 + l15][kd];
      f16x4 pa1 = *(const f16x4*)&Plds[hw * 16 + l15][16 + kd];
      const float* vbase = kvn + br * DN;
      #pragma unroll
      for (int dt = 0; dt < 16; ++dt) {
        const int cc = dv * 256 + dt * 16 + l15;
        f16x4 b0, b1;
        #pragma unroll
        for (int i = 0; i < 4; ++i) {
          b0[i] = (_Float16)vbase[(size_t)(kd + i) * DN + cc];
          b1[i] = (_Float16)vbase[(size_t)(16 + kd + i) * DN + cc];
        }
        acc[dt] = MFMA16(pa0, b0, acc[dt], 0, 0, 0);
        acc[dt] = MFMA16(pa1, b1, acc[dt], 0, 0, 0);
      }
    }
    // no barrier here: Plds(t) reads complete before any wave can write
    // Plds(t+1) (that write is gated by bar1 of tile t+1)
  }

  // ---- write partials: O (unnormalized, f16), m, l ----
  _Float16* pop = po + (size_t)(b * nc + c) * H_ * DN;
  #pragma unroll
  for (int dt = 0; dt < 16; ++dt)
    #pragma unroll
    for (int r = 0; r < 4; ++r)
      pop[(size_t)(hw * 16 + kd + r) * DN + dv * 256 + dt * 16 + l15] =
          (_Float16)acc[dt][r];
  const int fs = nsb & 1;
  if (tid < H_) {
    const size_t o = ((size_t)(b * nc + c) * H_ + tid) * 2;
    ml[o] = Mrun[fs][tid]; ml[o + 1] = Lrun[fs][tid];
  }
}

// Kernel 2: merge chunk partials per (b,h).
__global__ __launch_bounds__(256) void mla_reduce(
    const _Float16* __restrict__ po, const float* __restrict__ ml,
    const int* __restrict__ kseq, float* __restrict__ out,
    const int nc, const int chunk)
{
  const int bh = blockIdx.x;
  const int b = bh >> 5, h = bh & 31;
  const int klen = kseq[b];
  const int na = min(nc, (klen + chunk - 1) / chunk);
  const int tid = threadIdx.x;

  float M = NEG_INF;
  for (int c = 0; c < na; ++c)
    M = fmaxf(M, ml[((size_t)(b * nc + c) * H_ + h) * 2]);

  float s0 = 0.f, s1 = 0.f, den = 0.f;
  for (int c = 0; c < na; ++c) {
    const size_t o = ((size_t)(b * nc + c) * H_ + h) * 2;
    const float e = exp2f((ml[o] - M) * LOG2E);
    den += ml[o + 1] * e;
    const _Float16* p = po + ((size_t)(b * nc + c) * H_ + h) * DN;
    s0 += (float)p[tid] * e;
    s1 += (float)p[tid + 256] * e;
  }
  const float inv = 1.f / den;
  float* op = out + ((size_t)b * H_ + h) * DN;
  op[tid]       = s0 * inv;
  op[tid + 256] = s1 * inv;
}

extern "C" void kernel_launch(void* const* d_in, const int* in_sizes, int n_in,
                              void* d_out, int out_size, void* d_ws, size_t ws_size,
                              hipStream_t stream) {
  const float* qn  = (const float*)d_in[0];
  const float* qr  = (const float*)d_in[1];
  const float* kvn = (const float*)d_in[2];
  const float* kvr = (const float*)d_in[3];
  const int*  btab = (const int*)d_in[4];
  const int*  kseq = (const int*)d_in[6];
  float* out = (float*)d_out;

  // workspace-adaptive chunk count: nc chunks of 4096/nc keys
  int nc = 16;
  while (nc > 1 &&
         ((size_t)B_ * nc * H_ * DN * sizeof(_Float16) +
          (size_t)B_ * nc * H_ * 2 * sizeof(float)) > ws_size)
    nc >>= 1;
  const int chunk = MAXKV / nc;

  _Float16* po = (_Float16*)d_ws;                          // [B][nc][H][DN] f16
  float* ml = (float*)(po + (size_t)B_ * nc * H_ * DN);    // [B][nc][H][2]  f32

  mla_chunk<<<B_ * nc, 256, 0, stream>>>(qn, qr, kvn, kvr, btab, kseq,
                                         po, ml, nc, chunk);
  mla_reduce<<<B_ * H_, 256, 0, stream>>>(po, ml, kseq, out, nc, chunk);
}

// Round 11
// 163.263 us; speedup vs baseline: 2.1790x; 2.1790x over previous
//
#include <hip/hip_runtime.h>

#define B_ 64
#define H_ 32
#define DN 512
#define DR 64
#define BS 128
#define TK 32              // keys per tile
#define MAXKV 4096
#define LOG2E 1.44269504088896340736f
#define SCALE_ (1.0f/24.0f)   // 1/sqrt(576)
#define NEG_INF -1e30f

typedef float    f32x4 __attribute__((ext_vector_type(4)));
typedef _Float16 f16x4 __attribute__((ext_vector_type(4)));
typedef _Float16 f16x2 __attribute__((ext_vector_type(2)));

#define MFMA16 __builtin_amdgcn_mfma_f32_16x16x16f16

__device__ __forceinline__ f16x4 cvt4(f32x4 a) {
  f16x2 lo = __builtin_bit_cast(f16x2, __builtin_amdgcn_cvt_pkrtz(a[0], a[1]));
  f16x2 hi = __builtin_bit_cast(f16x2, __builtin_amdgcn_cvt_pkrtz(a[2], a[3]));
  f16x4 r; r[0] = lo[0]; r[1] = lo[1]; r[2] = hi[0]; r[3] = hi[1];
  return r;
}

// LDS-only barrier: drains lgkm, leaves global_load_lds (vmcnt) in flight.
__device__ __forceinline__ void ldsbar() {
  asm volatile("s_waitcnt lgkmcnt(0)" ::: "memory");
  __builtin_amdgcn_sched_barrier(0);
  __builtin_amdgcn_s_barrier();
  __builtin_amdgcn_sched_barrier(0);
}

// Counted wait for the current tile's DMA (18 loads/wave/tile), then barrier.
__device__ __forceinline__ void wait_tile(bool next_in_flight) {
  if (next_in_flight) asm volatile("s_waitcnt vmcnt(18)" ::: "memory");
  else                asm volatile("s_waitcnt vmcnt(0)"  ::: "memory");
  __builtin_amdgcn_sched_barrier(0);
  __builtin_amdgcn_s_barrier();
  __builtin_amdgcn_sched_barrier(0);
}

__device__ __forceinline__ void gl_lds16(const float* g, void* l) {
  __builtin_amdgcn_global_load_lds(
      (const __attribute__((address_space(1))) void*)g,
      (__attribute__((address_space(3))) void*)l, 16, 0, 0);
}

// Stage one 32-key tile (K-nope f32 [32][512] + rope [32][64]) into LDS via
// global_load_lds. LDS dest is linear (base + lane*16); the XOR swizzle
// (slot ^= key&7, 16B slots) is applied on the per-lane GLOBAL source, so
// LDS holds the swizzled layout; reads apply the same XOR (involution).
// 18 instructions per wave.
__device__ __forceinline__ void stage_tile(
    float* kb_lds, float* kr_lds,
    const float* kvn, const float* kvr,
    const size_t blkrow,  // blk*BS + row offset of key 0 of this tile
    const int w, const int lane)
{
  #pragma unroll
  for (int j = 0; j < 16; ++j) {
    const int I  = w * 16 + j;
    const int kl = I >> 1;                    // key-local 0..31
    const int sp = ((I & 1) << 6) + lane;     // physical 16B slot 0..127
    const int s  = sp ^ (kl & 7);             // content slot
    gl_lds16(kvn + (blkrow + kl) * DN + s * 4, (char*)kb_lds + I * 1024);
  }
  #pragma unroll
  for (int j = 0; j < 2; ++j) {
    const int I  = w * 2 + j;
    const int kl = I * 4 + (lane >> 4);       // key-local 0..31
    const int sp = lane & 15;                 // physical slot 0..15
    const int s  = sp ^ (kl & 7);
    gl_lds16(kvr + (blkrow + kl) * DR + s * 4, (char*)kr_lds + I * 1024);
  }
}

// Kernel 1: per (b, chunk) flash-decode partial. TK=32 tiles, 4 waves,
// double-buffered f32 K in LDS (DMA-staged), Q in f16 registers.
// 4 barriers/tile (wait + 3): softmax folded via redundant per-lane
// max-combine + Mrun/Lrun ping-pong.
__global__ __launch_bounds__(256, 1) void mla_chunk(
    const float* __restrict__ qn, const float* __restrict__ qr,
    const float* __restrict__ kvn, const float* __restrict__ kvr,
    const int* __restrict__ btab, const int* __restrict__ kseq,
    _Float16* __restrict__ po, float* __restrict__ ml,
    const int nc, const int chunk)
{
  // XCD swizzle: grid is divisible by 8; consecutive bc share an XCD.
  const int raw = blockIdx.x;
  const int bc  = (raw & 7) * ((int)gridDim.x >> 3) + (raw >> 3);
  const int b = bc / nc, c = bc - b * nc;
  const int klen = kseq[b];
  const int kbase = c * chunk;
  if (kbase >= klen) return;
  const int nvalid = min(chunk, klen - kbase);
  const int nsb = (nvalid + TK - 1) / TK;

  const int tid = threadIdx.x;
  const int w = tid >> 6, l = tid & 63, l15 = l & 15, lg = l >> 4;
  const int kd = lg * 4;
  const int wk = w >> 1, wh = w & 1;      // QK roles: key-half, head-half
  const int hw = w >> 1, dv = w & 1;      // PV roles: head-half, dim-half

  __shared__ float KB[2][TK][DN];         // 2 x 64 KB, swizzled
  __shared__ float KR[2][TK][DR];         // 2 x 8 KB, swizzled
  __shared__ _Float16 Plds[H_][40];       // 2.5 KB
  __shared__ float m_tab[2][H_], l_tab[2][H_];
  __shared__ float Mrun[2][H_], Lrun[2][H_];

  if (tid < H_) { Mrun[0][tid] = NEG_INF; Lrun[0][tid] = 0.f; }

  f32x4 acc[16];
  #pragma unroll
  for (int i = 0; i < 16; ++i) acc[i] = (f32x4){0.f, 0.f, 0.f, 0.f};

  // ---- Q fragments in f16 registers (once per block) ----
  // B-frag: col = l15 -> head wh*16+l15, k = kd+i -> dim d0*16+kd+i.
  f16x4 Qf[36];
  {
    const float* qn_ = qn + ((size_t)b * H_ + wh * 16 + l15) * DN + kd;
    const float* qr_ = qr + ((size_t)b * H_ + wh * 16 + l15) * DR + kd;
    #pragma unroll
    for (int i = 0; i < 32; ++i) Qf[i] = cvt4(*(const f32x4*)(qn_ + i * 16));
    #pragma unroll
    for (int i = 0; i < 4; ++i) Qf[32 + i] = cvt4(*(const f32x4*)(qr_ + i * 16));
  }

  // ---- prologue: stage tiles 0 and 1 ----
  {
    const size_t br0 = (size_t)btab[b * 32 + (kbase >> 7)] * BS + (kbase & (BS - 1));
    stage_tile(&KB[0][0][0], &KR[0][0][0], kvn, kvr, br0, w, l);
    if (nsb > 1) {
      const int kb1 = kbase + TK;
      const size_t br1 = (size_t)btab[b * 32 + (kb1 >> 7)] * BS + (kb1 & (BS - 1));
      stage_tile(&KB[1][0][0], &KR[1][0][0], kvn, kvr, br1, w, l);
    }
  }

  for (int t = 0; t < nsb; ++t) {
    const int buf = t & 1;
    const int cur = t & 1, nxt = cur ^ 1;
    wait_tile(t + 1 < nsb);     // tile t arrived (t+1 may stay in flight)

    // ---- Phase A: S^T = K . Q^T (from LDS, swizzled reads) ----
    const int k_ = wk * 16 + l15;                 // A-frag row: key-local
    const char* kA = (const char*)&KB[buf][0][0] + k_ * 2048;
    const char* rA = (const char*)&KR[buf][0][0] + k_ * 256;
    f32x4 s0 = {0.f, 0.f, 0.f, 0.f};
    #pragma unroll
    for (int d0 = 0; d0 < 32; ++d0) {
      f32x4 kv4 = *(const f32x4*)(kA + ((((d0 << 2) + lg) ^ (k_ & 7)) << 4));
      s0 = MFMA16(cvt4(kv4), Qf[d0], s0, 0, 0, 0);
    }
    #pragma unroll
    for (int d0 = 0; d0 < 4; ++d0) {
      f32x4 kv4 = *(const f32x4*)(rA + ((((d0 << 2) + lg) ^ (k_ & 7)) << 4));
      s0 = MFMA16(cvt4(kv4), Qf[32 + d0], s0, 0, 0, 0);
    }

    // ---- mask + per-wave max (16 keys per head) ----
    const int kb = kbase + t * TK;
    float v0[4];
    float mx = NEG_INF;
    #pragma unroll
    for (int r = 0; r < 4; ++r) {
      const bool ok = (kb + wk * 16 + kd + r) < klen;
      v0[r] = ok ? s0[r] * SCALE_ : NEG_INF;
      mx = fmaxf(mx, v0[r]);
    }
    mx = fmaxf(mx, __shfl_xor(mx, 16));
    mx = fmaxf(mx, __shfl_xor(mx, 32));
    if (lg == 0) m_tab[wk][wh * 16 + l15] = mx;
    ldsbar();                                   // bar1: m_tab visible

    // ---- softmax: redundant per-lane max-combine (no serial phase) ----
    const int hC = wh * 16 + l15;
    const float moC = Mrun[cur][hC];
    const float mnC = fmaxf(fmaxf(m_tab[0][hC], m_tab[1][hC]), moC);
    float p0[4], ls = 0.f;
    #pragma unroll
    for (int r = 0; r < 4; ++r) { p0[r] = exp2f((v0[r] - mnC) * LOG2E); ls += p0[r]; }
    ls += __shfl_xor(ls, 16); ls += __shfl_xor(ls, 32);
    if (lg == 0) l_tab[wk][hC] = ls;
    f16x4 pk;
    #pragma unroll
    for (int r = 0; r < 4; ++r) pk[r] = (_Float16)p0[r];
    *(f16x4*)&Plds[hC][wk * 16 + kd] = pk;
    // rescale acc: fact recomputed per PV-head redundantly
    #pragma unroll
    for (int r = 0; r < 4; ++r) {
      const int h = hw * 16 + kd + r;
      const float mo = Mrun[cur][h];
      const float mn = fmaxf(fmaxf(m_tab[0][h], m_tab[1][h]), mo);
      const float f = exp2f((mo - mn) * LOG2E);
      #pragma unroll
      for (int dt = 0; dt < 16; ++dt) acc[dt][r] *= f;
    }
    if (tid < H_) {                            // Mrun ping-pong update
      const float mo = Mrun[cur][tid];
      Mrun[nxt][tid] = fmaxf(fmaxf(m_tab[0][tid], m_tab[1][tid]), mo);
    }
    ldsbar();                                   // bar2: P/l_tab/Mrun visible

    if (tid < H_) {                            // Lrun ping-pong update
      const float mo = Mrun[cur][tid], mn = Mrun[nxt][tid];
      const float f = exp2f((mo - mn) * LOG2E);
      Lrun[nxt][tid] = Lrun[cur][tid] * f + l_tab[0][tid] + l_tab[1][tid];
    }

    // ---- Phase E: PV. Wave (hw, dv) -> O[16 heads][256 dims] ----
    #pragma unroll
    for (int ks = 0; ks < 2; ++ks) {
      f16x4 pa = *(const f16x4*)&Plds[hw * 16 + l15][ks * 16 + kd];
      #pragma unroll
      for (int dt = 0; dt < 16; ++dt) {
        const int cc = dv * 256 + dt * 16 + l15;   // dim column
        float b4[4];
        #pragma unroll
        for (int i = 0; i < 4; ++i) {
          const int k2 = ks * 16 + kd + i;         // key (k-dim)
          b4[i] = *(const float*)((const char*)&KB[buf][0][0] + k2 * 2048
                    + ((((cc >> 2) ^ (k2 & 7)) << 4) + ((cc & 3) << 2)));
        }
        f16x4 bv;
        bv[0] = (_Float16)b4[0]; bv[1] = (_Float16)b4[1];
        bv[2] = (_Float16)b4[2]; bv[3] = (_Float16)b4[3];
        acc[dt] = MFMA16(pa, bv, acc[dt], 0, 0, 0);
      }
    }
    ldsbar();   // bar3: all reads of buf done block-wide

    // ---- stage tile t+2 into this buffer (stays in flight) ----
    if (t + 2 < nsb) {
      const int kb2 = kbase + (t + 2) * TK;
      const size_t br2 = (size_t)btab[b * 32 + (kb2 >> 7)] * BS + (kb2 & (BS - 1));
      stage_tile(&KB[buf][0][0], &KR[buf][0][0], kvn, kvr, br2, w, l);
    }
  }

  // ---- write partials: O (unnormalized, f16), m, l ----
  _Float16* pop = po + (size_t)(b * nc + c) * H_ * DN;
  #pragma unroll
  for (int dt = 0; dt < 16; ++dt)
    #pragma unroll
    for (int r = 0; r < 4; ++r)
      pop[(size_t)(hw * 16 + kd + r) * DN + dv * 256 + dt * 16 + l15] =
          (_Float16)acc[dt][r];
  const int fs = nsb & 1;
  if (tid < H_) {
    const size_t o = ((size_t)(b * nc + c) * H_ + tid) * 2;
    ml[o] = Mrun[fs][tid]; ml[o + 1] = Lrun[fs][tid];
  }
}

// Kernel 2: merge chunk partials per (b,h).
__global__ __launch_bounds__(256) void mla_reduce(
    const _Float16* __restrict__ po, const float* __restrict__ ml,
    const int* __restrict__ kseq, float* __restrict__ out,
    const int nc, const int chunk)
{
  const int bh = blockIdx.x;
  const int b = bh >> 5, h = bh & 31;
  const int klen = kseq[b];
  const int na = min(nc, (klen + chunk - 1) / chunk);
  const int tid = threadIdx.x;

  float M = NEG_INF;
  for (int c = 0; c < na; ++c)
    M = fmaxf(M, ml[((size_t)(b * nc + c) * H_ + h) * 2]);

  float s0 = 0.f, s1 = 0.f, den = 0.f;
  for (int c = 0; c < na; ++c) {
    const size_t o = ((size_t)(b * nc + c) * H_ + h) * 2;
    const float e = exp2f((ml[o] - M) * LOG2E);
    den += ml[o + 1] * e;
    const _Float16* p = po + ((size_t)(b * nc + c) * H_ + h) * DN;
    s0 += (float)p[tid] * e;
    s1 += (float)p[tid + 256] * e;
  }
  const float inv = 1.f / den;
  float* op = out + ((size_t)b * H_ + h) * DN;
  op[tid]       = s0 * inv;
  op[tid + 256] = s1 * inv;
}

extern "C" void kernel_launch(void* const* d_in, const int* in_sizes, int n_in,
                              void* d_out, int out_size, void* d_ws, size_t ws_size,
                              hipStream_t stream) {
  const float* qn  = (const float*)d_in[0];
  const float* qr  = (const float*)d_in[1];
  const float* kvn = (const float*)d_in[2];
  const float* kvr = (const float*)d_in[3];
  const int*  btab = (const int*)d_in[4];
  const int*  kseq = (const int*)d_in[6];
  float* out = (float*)d_out;

  // workspace-adaptive chunk count: nc chunks of 4096/nc keys
  int nc = 16;
  while (nc > 1 &&
         ((size_t)B_ * nc * H_ * DN * sizeof(_Float16) +
          (size_t)B_ * nc * H_ * 2 * sizeof(float)) > ws_size)
    nc >>= 1;
  const int chunk = MAXKV / nc;

  _Float16* po = (_Float16*)d_ws;                          // [B][nc][H][DN] f16
  float* ml = (float*)(po + (size_t)B_ * nc * H_ * DN);    // [B][nc][H][2]  f32

  mla_chunk<<<B_ * nc, 256, 0, stream>>>(qn, qr, kvn, kvr, btab, kseq,
                                         po, ml, nc, chunk);
  mla_reduce<<<B_ * H_, 256, 0, stream>>>(po, ml, kseq, out, nc, chunk);
}

// Round 12
// 161.500 us; speedup vs baseline: 2.2028x; 1.0109x over previous
//
#include <hip/hip_runtime.h>

#define B_ 64
#define H_ 32
#define DN 512
#define DR 64
#define BS 128
#define TK 32              // keys per tile
#define MAXKV 4096
#define LOG2E 1.44269504088896340736f
#define SCALE_ (1.0f/24.0f)   // 1/sqrt(576)
#define NEG_INF -1e30f

typedef float    f32x4 __attribute__((ext_vector_type(4)));
typedef _Float16 f16x4 __attribute__((ext_vector_type(4)));
typedef _Float16 f16x2 __attribute__((ext_vector_type(2)));

#define MFMA16 __builtin_amdgcn_mfma_f32_16x16x16f16

__device__ __forceinline__ f16x4 cvt4(f32x4 a) {
  f16x2 lo = __builtin_bit_cast(f16x2, __builtin_amdgcn_cvt_pkrtz(a[0], a[1]));
  f16x2 hi = __builtin_bit_cast(f16x2, __builtin_amdgcn_cvt_pkrtz(a[2], a[3]));
  f16x4 r; r[0] = lo[0]; r[1] = lo[1]; r[2] = hi[0]; r[3] = hi[1];
  return r;
}

// LDS-only barrier: drains lgkm, leaves global_load_lds (vmcnt) in flight.
__device__ __forceinline__ void ldsbar() {
  asm volatile("s_waitcnt lgkmcnt(0)" ::: "memory");
  __builtin_amdgcn_sched_barrier(0);
  __builtin_amdgcn_s_barrier();
  __builtin_amdgcn_sched_barrier(0);
}

// Counted wait for the current tile's DMA (9 loads/wave/tile), then barrier.
__device__ __forceinline__ void wait_tile(bool next_in_flight) {
  if (next_in_flight) asm volatile("s_waitcnt vmcnt(9)" ::: "memory");
  else                asm volatile("s_waitcnt vmcnt(0)" ::: "memory");
  __builtin_amdgcn_sched_barrier(0);
  __builtin_amdgcn_s_barrier();
  __builtin_amdgcn_sched_barrier(0);
}

__device__ __forceinline__ void gl_lds16(const float* g, void* l) {
  __builtin_amdgcn_global_load_lds(
      (const __attribute__((address_space(1))) void*)g,
      (__attribute__((address_space(3))) void*)l, 16, 0, 0);
}

// Stage one 32-key tile (K-nope f32 [32][512] + rope [32][64]) into LDS via
// global_load_lds, spread over 8 waves (9 instructions each). LDS dest is
// linear (base + lane*16); the XOR swizzle (16B slot ^= key&7) is applied
// on the per-lane GLOBAL source; reads use the same XOR (involution).
__device__ __forceinline__ void stage_tile8(
    float* kb_lds, float* kr_lds,
    const float* kvn, const float* kvr,
    const size_t blkrow, const int w, const int lane)
{
  #pragma unroll
  for (int j = 0; j < 8; ++j) {
    const int I  = w * 8 + j;                 // half-row 0..63
    const int kl = I >> 1;                    // key-local 0..31
    const int sp = ((I & 1) << 6) + lane;     // physical 16B slot 0..127
    const int s  = sp ^ (kl & 7);             // content slot
    gl_lds16(kvn + (blkrow + kl) * DN + s * 4, (char*)kb_lds + I * 1024);
  }
  {
    const int I  = w;                         // quad-row 0..7
    const int kl = I * 4 + (lane >> 4);       // key-local 0..31
    const int sp = lane & 15;                 // physical slot 0..15
    const int s  = sp ^ (kl & 7);
    gl_lds16(kvr + (blkrow + kl) * DR + s * 4, (char*)kr_lds + I * 1024);
  }
}

// Kernel 1: per (b, chunk) flash-decode partial. TK=32 tiles, EIGHT waves
// (512 threads) -> 2 waves/SIMD for latency hiding. Double-buffered f32 K
// in LDS (DMA-staged). QK: wave (wk,wh,wd) computes a 16-key x 16-head
// partial over 288 dims; halves summed via Spart LDS exchange. PV: wave
// (hp,dq) computes [16 heads][128 dims]. LDS 159.5 KB.
__global__ __launch_bounds__(512, 1) void mla_chunk(
    const float* __restrict__ qn, const float* __restrict__ qr,
    const float* __restrict__ kvn, const float* __restrict__ kvr,
    const int* __restrict__ btab, const int* __restrict__ kseq,
    _Float16* __restrict__ po, float* __restrict__ ml,
    const int nc, const int chunk)
{
  const int bc = blockIdx.x;
  const int b = bc / nc, c = bc - b * nc;
  const int klen = kseq[b];
  const int kbase = c * chunk;
  if (kbase >= klen) return;
  const int nvalid = min(chunk, klen - kbase);
  const int nsb = (nvalid + TK - 1) / TK;

  const int tid = threadIdx.x;
  const int w = tid >> 6, l = tid & 63, l15 = l & 15, lg = l >> 4;
  const int kd = lg * 4;
  const int wk = w & 1, wh = (w >> 1) & 1, wd = w >> 2;  // QK roles
  const int hp = w >> 2, dq = w & 3;                     // PV roles

  __shared__ float KB[2][TK][DN];          // 131,072 B, swizzled
  __shared__ float KR[2][TK][DR];          //  16,384 B, swizzled
  __shared__ float Spart[2][TK][H_ + 1];   //   8,448 B (padded rows)
  __shared__ _Float16 Plds[H_][40];        //   2,560 B
  __shared__ float m_tab[2][H_], l_tab[2][H_];
  __shared__ float Mrun[2][H_], Lrun[2][H_];

  if (tid < H_) { Mrun[0][tid] = NEG_INF; Lrun[0][tid] = 0.f; }

  f32x4 acc[8];
  #pragma unroll
  for (int i = 0; i < 8; ++i) acc[i] = (f32x4){0.f, 0.f, 0.f, 0.f};

  // ---- Q fragments in f16 regs: this wave's 288-dim half ----
  // B-frag: col = l15 -> head wh*16+l15, k = kd+i.
  f16x4 Qf[18];
  {
    const float* qn_ = qn + ((size_t)b * H_ + wh * 16 + l15) * DN + kd;
    const float* qr_ = qr + ((size_t)b * H_ + wh * 16 + l15) * DR + kd;
    #pragma unroll
    for (int i = 0; i < 16; ++i)
      Qf[i] = cvt4(*(const f32x4*)(qn_ + (wd * 16 + i) * 16));
    #pragma unroll
    for (int i = 0; i < 2; ++i)
      Qf[16 + i] = cvt4(*(const f32x4*)(qr_ + (wd * 2 + i) * 16));
  }

  // ---- prologue: stage tiles 0 and 1 ----
  {
    const size_t br0 = (size_t)btab[b * 32 + (kbase >> 7)] * BS + (kbase & (BS - 1));
    stage_tile8(&KB[0][0][0], &KR[0][0][0], kvn, kvr, br0, w, l);
    if (nsb > 1) {
      const int kb1 = kbase + TK;
      const size_t br1 = (size_t)btab[b * 32 + (kb1 >> 7)] * BS + (kb1 & (BS - 1));
      stage_tile8(&KB[1][0][0], &KR[1][0][0], kvn, kvr, br1, w, l);
    }
  }

  for (int t = 0; t < nsb; ++t) {
    const int buf = t & 1;
    const int cur = t & 1, nxt = cur ^ 1;
    wait_tile(t + 1 < nsb);     // tile t landed (t+1 stays in flight)

    // ---- QK^T partial: 16 keys x 16 heads over this wave's dims ----
    const int k_ = wk * 16 + l15;
    const char* kA = (const char*)&KB[buf][0][0] + k_ * 2048;
    const char* rA = (const char*)&KR[buf][0][0] + k_ * 256;
    const int x7 = k_ & 7;
    f32x4 sA = {0.f,0.f,0.f,0.f}, sB = {0.f,0.f,0.f,0.f};
    #pragma unroll
    for (int i = 0; i < 16; i += 2) {
      f32x4 k0 = *(const f32x4*)(kA + ((((wd * 16 + i) * 4 + lg) ^ x7) << 4));
      f32x4 k1 = *(const f32x4*)(kA + ((((wd * 16 + i + 1) * 4 + lg) ^ x7) << 4));
      sA = MFMA16(cvt4(k0), Qf[i],     sA, 0, 0, 0);
      sB = MFMA16(cvt4(k1), Qf[i + 1], sB, 0, 0, 0);
    }
    #pragma unroll
    for (int i = 0; i < 2; ++i) {
      f32x4 k0 = *(const f32x4*)(rA + ((((wd * 2 + i) * 4 + lg) ^ x7) << 4));
      sA = MFMA16(cvt4(k0), Qf[16 + i], sA, 0, 0, 0);
    }
    // D: row(key-in-tile) = kd+r, col(head-in-half) = l15.
    #pragma unroll
    for (int r = 0; r < 4; ++r)
      Spart[wd][wk * 16 + kd + r][wh * 16 + l15] = sA[r] + sB[r];
    ldsbar();                                   // bar1: Spart visible

    // ---- sum halves + mask + tile max (wd==0 waves only) ----
    const int kb = kbase + t * TK;
    const int hC = wh * 16 + l15;
    float v0[4];
    if (wd == 0) {
      float mx = NEG_INF;
      #pragma unroll
      for (int r = 0; r < 4; ++r) {
        const int key = wk * 16 + kd + r;
        const float sv = (Spart[0][key][hC] + Spart[1][key][hC]) * SCALE_;
        v0[r] = (kb + key < klen) ? sv : NEG_INF;
        mx = fmaxf(mx, v0[r]);
      }
      mx = fmaxf(mx, __shfl_xor(mx, 16));
      mx = fmaxf(mx, __shfl_xor(mx, 32));
      if (lg == 0) m_tab[wk][hC] = mx;
    }
    ldsbar();                                   // bar2: m_tab visible

    // ---- P = exp(s - M) (wd==0); all waves rescale acc ----
    if (wd == 0) {
      const float moC = Mrun[cur][hC];
      const float mnC = fmaxf(fmaxf(m_tab[0][hC], m_tab[1][hC]), moC);
      float p0[4], ls = 0.f;
      #pragma unroll
      for (int r = 0; r < 4; ++r) { p0[r] = exp2f((v0[r] - mnC) * LOG2E); ls += p0[r]; }
      ls += __shfl_xor(ls, 16); ls += __shfl_xor(ls, 32);
      if (lg == 0) l_tab[wk][hC] = ls;
      f16x4 pk;
      #pragma unroll
      for (int r = 0; r < 4; ++r) pk[r] = (_Float16)p0[r];
      *(f16x4*)&Plds[hC][wk * 16 + kd] = pk;
    }
    #pragma unroll
    for (int r = 0; r < 4; ++r) {
      const int h = hp * 16 + kd + r;
      const float mo = Mrun[cur][h];
      const float mn = fmaxf(fmaxf(m_tab[0][h], m_tab[1][h]), mo);
      const float f = exp2f((mo - mn) * LOG2E);
      #pragma unroll
      for (int dt = 0; dt < 8; ++dt) acc[dt][r] *= f;
    }
    if (tid < H_) {                            // Mrun ping-pong update
      const float mo = Mrun[cur][tid];
      Mrun[nxt][tid] = fmaxf(fmaxf(m_tab[0][tid], m_tab[1][tid]), mo);
    }
    ldsbar();                                   // bar3: Plds/Mrun visible

    if (tid < H_) {                            // Lrun ping-pong update
      const float mo = Mrun[cur][tid], mn = Mrun[nxt][tid];
      const float f = exp2f((mo - mn) * LOG2E);
      Lrun[nxt][tid] = Lrun[cur][tid] * f + l_tab[0][tid] + l_tab[1][tid];
    }

    // ---- PV: wave (hp, dq) -> O[16 heads][128 dims], V from K-LDS ----
    #pragma unroll
    for (int ks = 0; ks < 2; ++ks) {
      f16x4 pa = *(const f16x4*)&Plds[hp * 16 + l15][ks * 16 + kd];
      #pragma unroll
      for (int dt = 0; dt < 8; ++dt) {
        const int cc = dq * 128 + dt * 16 + l15;   // dim column
        float b4[4];
        #pragma unroll
        for (int i = 0; i < 4; ++i) {
          const int k2 = ks * 16 + kd + i;         // key (k-dim)
          b4[i] = *(const float*)((const char*)&KB[buf][0][0] + k2 * 2048
                    + ((((cc >> 2) ^ (k2 & 7)) << 4) + ((cc & 3) << 2)));
        }
        f16x4 bv;
        bv[0] = (_Float16)b4[0]; bv[1] = (_Float16)b4[1];
        bv[2] = (_Float16)b4[2]; bv[3] = (_Float16)b4[3];
        acc[dt] = MFMA16(pa, bv, acc[dt], 0, 0, 0);
      }
    }
    ldsbar();                                   // bar4: buf reads done

    // ---- stage tile t+2 into this buffer (stays in flight) ----
    if (t + 2 < nsb) {
      const int kb2 = kbase + (t + 2) * TK;
      const size_t br2 = (size_t)btab[b * 32 + (kb2 >> 7)] * BS + (kb2 & (BS - 1));
      stage_tile8(&KB[buf][0][0], &KR[buf][0][0], kvn, kvr, br2, w, l);
    }
  }

  // ---- write partials: O (unnormalized, f16), m, l ----
  _Float16* pop = po + (size_t)(b * nc + c) * H_ * DN;
  #pragma unroll
  for (int dt = 0; dt < 8; ++dt)
    #pragma unroll
    for (int r = 0; r < 4; ++r)
      pop[(size_t)(hp * 16 + kd + r) * DN + dq * 128 + dt * 16 + l15] =
          (_Float16)acc[dt][r];
  const int fs = nsb & 1;
  if (tid < H_) {
    const size_t o = ((size_t)(b * nc + c) * H_ + tid) * 2;
    ml[o] = Mrun[fs][tid]; ml[o + 1] = Lrun[fs][tid];
  }
}

// Kernel 2: merge chunk partials per (b,h).
__global__ __launch_bounds__(256) void mla_reduce(
    const _Float16* __restrict__ po, const float* __restrict__ ml,
    const int* __restrict__ kseq, float* __restrict__ out,
    const int nc, const int chunk)
{
  const int bh = blockIdx.x;
  const int b = bh >> 5, h = bh & 31;
  const int klen = kseq[b];
  const int na = min(nc, (klen + chunk - 1) / chunk);
  const int tid = threadIdx.x;

  float M = NEG_INF;
  for (int c = 0; c < na; ++c)
    M = fmaxf(M, ml[((size_t)(b * nc + c) * H_ + h) * 2]);

  float s0 = 0.f, s1 = 0.f, den = 0.f;
  for (int c = 0; c < na; ++c) {
    const size_t o = ((size_t)(b * nc + c) * H_ + h) * 2;
    const float e = exp2f((ml[o] - M) * LOG2E);
    den += ml[o + 1] * e;
    const _Float16* p = po + ((size_t)(b * nc + c) * H_ + h) * DN;
    s0 += (float)p[tid] * e;
    s1 += (float)p[tid + 256] * e;
  }
  const float inv = 1.f / den;
  float* op = out + ((size_t)b * H_ + h) * DN;
  op[tid]       = s0 * inv;
  op[tid + 256] = s1 * inv;
}

extern "C" void kernel_launch(void* const* d_in, const int* in_sizes, int n_in,
                              void* d_out, int out_size, void* d_ws, size_t ws_size,
                              hipStream_t stream) {
  const float* qn  = (const float*)d_in[0];
  const float* qr  = (const float*)d_in[1];
  const float* kvn = (const float*)d_in[2];
  const float* kvr = (const float*)d_in[3];
  const int*  btab = (const int*)d_in[4];
  const int*  kseq = (const int*)d_in[6];
  float* out = (float*)d_out;

  // workspace-adaptive chunk count: nc chunks of 4096/nc keys
  int nc = 16;
  while (nc > 1 &&
         ((size_t)B_ * nc * H_ * DN * sizeof(_Float16) +
          (size_t)B_ * nc * H_ * 2 * sizeof(float)) > ws_size)
    nc >>= 1;
  const int chunk = MAXKV / nc;

  _Float16* po = (_Float16*)d_ws;                          // [B][nc][H][DN] f16
  float* ml = (float*)(po + (size_t)B_ * nc * H_ * DN);    // [B][nc][H][2]  f32

  mla_chunk<<<B_ * nc, 512, 0, stream>>>(qn, qr, kvn, kvr, btab, kseq,
                                         po, ml, nc, chunk);
  mla_reduce<<<B_ * H_, 256, 0, stream>>>(po, ml, kseq, out, nc, chunk);
}

// Round 13
// 161.203 us; speedup vs baseline: 2.2068x; 1.0018x over previous
//
#include <hip/hip_runtime.h>

#define B_ 64
#define H_ 32
#define DN 512
#define DR 64
#define BS 128
#define TK 32              // keys per tile
#define MAXKV 4096
#define LOG2E 1.44269504088896340736f
#define SCALE_ (1.0f/24.0f)   // 1/sqrt(576)
#define NEG_INF -1e30f

typedef float    f32x4 __attribute__((ext_vector_type(4)));
typedef _Float16 f16x4 __attribute__((ext_vector_type(4)));
typedef _Float16 f16x2 __attribute__((ext_vector_type(2)));

#define MFMA16 __builtin_amdgcn_mfma_f32_16x16x16f16

__device__ __forceinline__ f16x4 cvt4(f32x4 a) {
  f16x2 lo = __builtin_bit_cast(f16x2, __builtin_amdgcn_cvt_pkrtz(a[0], a[1]));
  f16x2 hi = __builtin_bit_cast(f16x2, __builtin_amdgcn_cvt_pkrtz(a[2], a[3]));
  f16x4 r; r[0] = lo[0]; r[1] = lo[1]; r[2] = hi[0]; r[3] = hi[1];
  return r;
}

// LDS-ordering barrier WITHOUT vmcnt drain and WITHOUT sched_barrier
// pinning: the "memory" clobber keeps LDS/DMA ops inside their phase,
// but the compiler is free to schedule within phases.
__device__ __forceinline__ void ldsbar() {
  asm volatile("s_waitcnt lgkmcnt(0)\n\ts_barrier" ::: "memory");
}

// Counted wait for the current tile's DMA (9 loads/wave/tile), then barrier.
__device__ __forceinline__ void wait_tile(bool next_in_flight) {
  if (next_in_flight)
    asm volatile("s_waitcnt vmcnt(9) lgkmcnt(0)\n\ts_barrier" ::: "memory");
  else
    asm volatile("s_waitcnt vmcnt(0) lgkmcnt(0)\n\ts_barrier" ::: "memory");
}

__device__ __forceinline__ void gl_lds16(const float* g, void* l) {
  __builtin_amdgcn_global_load_lds(
      (const __attribute__((address_space(1))) void*)g,
      (__attribute__((address_space(3))) void*)l, 16, 0, 0);
}

// Stage one 32-key tile (K-nope f32 [32][512] + rope [32][64]) into LDS via
// global_load_lds, spread over 8 waves (9 instructions each). LDS dest is
// linear (base + lane*16); the XOR swizzle (16B slot ^= key&7) is applied
// on the per-lane GLOBAL source; reads use the same XOR (involution).
__device__ __forceinline__ void stage_tile8(
    float* kb_lds, float* kr_lds,
    const float* kvn, const float* kvr,
    const size_t blkrow, const int w, const int lane)
{
  #pragma unroll
  for (int j = 0; j < 8; ++j) {
    const int I  = w * 8 + j;                 // half-row 0..63
    const int kl = I >> 1;                    // key-local 0..31
    const int sp = ((I & 1) << 6) + lane;     // physical 16B slot 0..127
    const int s  = sp ^ (kl & 7);             // content slot
    gl_lds16(kvn + (blkrow + kl) * DN + s * 4, (char*)kb_lds + I * 1024);
  }
  {
    const int I  = w;                         // quad-row 0..7
    const int kl = I * 4 + (lane >> 4);       // key-local 0..31
    const int sp = lane & 15;                 // physical slot 0..15
    const int s  = sp ^ (kl & 7);
    gl_lds16(kvr + (blkrow + kl) * DR + s * 4, (char*)kr_lds + I * 1024);
  }
}

// Kernel 1: per (b, chunk) flash-decode partial. TK=32 tiles, EIGHT waves
// (512 threads) -> 2 waves/SIMD. Double-buffered f32 K in LDS (DMA-staged,
// counted vmcnt so next tile's DMA stays in flight across all phases).
// QK: wave (wk,wh,wd) computes a 16-key x 16-head partial over 288 dims;
// halves summed via Spart exchange. PV: wave (hp,dq) -> [16 h][128 d].
__global__ __launch_bounds__(512, 1) void mla_chunk(
    const float* __restrict__ qn, const float* __restrict__ qr,
    const float* __restrict__ kvn, const float* __restrict__ kvr,
    const int* __restrict__ btab, const int* __restrict__ kseq,
    _Float16* __restrict__ po, float* __restrict__ ml,
    const int nc, const int chunk)
{
  const int bc = blockIdx.x;
  const int b = bc / nc, c = bc - b * nc;
  const int klen = kseq[b];
  const int kbase = c * chunk;
  if (kbase >= klen) return;
  const int nvalid = min(chunk, klen - kbase);
  const int nsb = (nvalid + TK - 1) / TK;

  const int tid = threadIdx.x;
  const int w = tid >> 6, l = tid & 63, l15 = l & 15, lg = l >> 4;
  const int kd = lg * 4;
  const int wk = w & 1, wh = (w >> 1) & 1, wd = w >> 2;  // QK roles
  const int hp = w >> 2, dq = w & 3;                     // PV roles

  __shared__ float KB[2][TK][DN];          // 131,072 B, swizzled
  __shared__ float KR[2][TK][DR];          //  16,384 B, swizzled
  __shared__ float Spart[2][TK][H_ + 1];   //   8,448 B (padded rows)
  __shared__ _Float16 Plds[H_][40];        //   2,560 B
  __shared__ float m_tab[2][H_], l_tab[2][H_];
  __shared__ float Mrun[2][H_], Lrun[2][H_];

  if (tid < H_) { Mrun[0][tid] = NEG_INF; Lrun[0][tid] = 0.f; }

  f32x4 acc[8];
  #pragma unroll
  for (int i = 0; i < 8; ++i) acc[i] = (f32x4){0.f, 0.f, 0.f, 0.f};

  // ---- Q fragments in f16 regs: this wave's 288-dim half ----
  // B-frag: col = l15 -> head wh*16+l15, k = kd+i.
  f16x4 Qf[18];
  {
    const float* qn_ = qn + ((size_t)b * H_ + wh * 16 + l15) * DN + kd;
    const float* qr_ = qr + ((size_t)b * H_ + wh * 16 + l15) * DR + kd;
    #pragma unroll
    for (int i = 0; i < 16; ++i)
      Qf[i] = cvt4(*(const f32x4*)(qn_ + (wd * 16 + i) * 16));
    #pragma unroll
    for (int i = 0; i < 2; ++i)
      Qf[16 + i] = cvt4(*(const f32x4*)(qr_ + (wd * 2 + i) * 16));
  }

  // ---- prologue: stage tiles 0 and 1 ----
  {
    const size_t br0 = (size_t)btab[b * 32 + (kbase >> 7)] * BS + (kbase & (BS - 1));
    stage_tile8(&KB[0][0][0], &KR[0][0][0], kvn, kvr, br0, w, l);
    if (nsb > 1) {
      const int kb1 = kbase + TK;
      const size_t br1 = (size_t)btab[b * 32 + (kb1 >> 7)] * BS + (kb1 & (BS - 1));
      stage_tile8(&KB[1][0][0], &KR[1][0][0], kvn, kvr, br1, w, l);
    }
  }

  for (int t = 0; t < nsb; ++t) {
    const int buf = t & 1;
    const int cur = t & 1, nxt = cur ^ 1;
    wait_tile(t + 1 < nsb);     // tile t landed (t+1 stays in flight)

    // ---- QK^T partial: 16 keys x 16 heads over this wave's dims ----
    const int k_ = wk * 16 + l15;
    const char* kA = (const char*)&KB[buf][0][0] + k_ * 2048;
    const char* rA = (const char*)&KR[buf][0][0] + k_ * 256;
    const int x7 = k_ & 7;
    f32x4 sA = {0.f,0.f,0.f,0.f}, sB = {0.f,0.f,0.f,0.f};
    #pragma unroll
    for (int i = 0; i < 16; i += 2) {
      f32x4 k0 = *(const f32x4*)(kA + ((((wd * 16 + i) * 4 + lg) ^ x7) << 4));
      f32x4 k1 = *(const f32x4*)(kA + ((((wd * 16 + i + 1) * 4 + lg) ^ x7) << 4));
      sA = MFMA16(cvt4(k0), Qf[i],     sA, 0, 0, 0);
      sB = MFMA16(cvt4(k1), Qf[i + 1], sB, 0, 0, 0);
    }
    #pragma unroll
    for (int i = 0; i < 2; ++i) {
      f32x4 k0 = *(const f32x4*)(rA + ((((wd * 2 + i) * 4 + lg) ^ x7) << 4));
      sA = MFMA16(cvt4(k0), Qf[16 + i], sA, 0, 0, 0);
    }
    // D: row(key-in-tile) = kd+r, col(head-in-half) = l15.
    #pragma unroll
    for (int r = 0; r < 4; ++r)
      Spart[wd][wk * 16 + kd + r][wh * 16 + l15] = sA[r] + sB[r];
    ldsbar();                                   // bar1: Spart visible

    // ---- sum halves + mask + tile max (wd==0 waves only) ----
    const int kb = kbase + t * TK;
    const int hC = wh * 16 + l15;
    float v0[4];
    if (wd == 0) {
      float mx = NEG_INF;
      #pragma unroll
      for (int r = 0; r < 4; ++r) {
        const int key = wk * 16 + kd + r;
        const float sv = (Spart[0][key][hC] + Spart[1][key][hC]) * SCALE_;
        v0[r] = (kb + key < klen) ? sv : NEG_INF;
        mx = fmaxf(mx, v0[r]);
      }
      mx = fmaxf(mx, __shfl_xor(mx, 16));
      mx = fmaxf(mx, __shfl_xor(mx, 32));
      if (lg == 0) m_tab[wk][hC] = mx;
    }
    ldsbar();                                   // bar2: m_tab visible

    // ---- P = exp(s - M) (wd==0); all waves rescale acc ----
    if (wd == 0) {
      const float moC = Mrun[cur][hC];
      const float mnC = fmaxf(fmaxf(m_tab[0][hC], m_tab[1][hC]), moC);
      float p0[4], ls = 0.f;
      #pragma unroll
      for (int r = 0; r < 4; ++r) { p0[r] = exp2f((v0[r] - mnC) * LOG2E); ls += p0[r]; }
      ls += __shfl_xor(ls, 16); ls += __shfl_xor(ls, 32);
      if (lg == 0) l_tab[wk][hC] = ls;
      f16x4 pk;
      #pragma unroll
      for (int r = 0; r < 4; ++r) pk[r] = (_Float16)p0[r];
      *(f16x4*)&Plds[hC][wk * 16 + kd] = pk;
    }
    #pragma unroll
    for (int r = 0; r < 4; ++r) {
      const int h = hp * 16 + kd + r;
      const float mo = Mrun[cur][h];
      const float mn = fmaxf(fmaxf(m_tab[0][h], m_tab[1][h]), mo);
      const float f = exp2f((mo - mn) * LOG2E);
      #pragma unroll
      for (int dt = 0; dt < 8; ++dt) acc[dt][r] *= f;
    }
    if (tid < H_) {                            // Mrun ping-pong update
      const float mo = Mrun[cur][tid];
      Mrun[nxt][tid] = fmaxf(fmaxf(m_tab[0][tid], m_tab[1][tid]), mo);
    }
    ldsbar();                                   // bar3: Plds/Mrun visible

    if (tid < H_) {                            // Lrun ping-pong update
      const float mo = Mrun[cur][tid], mn = Mrun[nxt][tid];
      const float f = exp2f((mo - mn) * LOG2E);
      Lrun[nxt][tid] = Lrun[cur][tid] * f + l_tab[0][tid] + l_tab[1][tid];
    }

    // ---- PV: wave (hp, dq) -> O[16 heads][128 dims], V from K-LDS ----
    #pragma unroll
    for (int ks = 0; ks < 2; ++ks) {
      f16x4 pa = *(const f16x4*)&Plds[hp * 16 + l15][ks * 16 + kd];
      #pragma unroll
      for (int dt = 0; dt < 8; ++dt) {
        const int cc = dq * 128 + dt * 16 + l15;   // dim column
        float b4[4];
        #pragma unroll
        for (int i = 0; i < 4; ++i) {
          const int k2 = ks * 16 + kd + i;         // key (k-dim)
          b4[i] = *(const float*)((const char*)&KB[buf][0][0] + k2 * 2048
                    + ((((cc >> 2) ^ (k2 & 7)) << 4) + ((cc & 3) << 2)));
        }
        f16x4 bv;
        bv[0] = (_Float16)b4[0]; bv[1] = (_Float16)b4[1];
        bv[2] = (_Float16)b4[2]; bv[3] = (_Float16)b4[3];
        acc[dt] = MFMA16(pa, bv, acc[dt], 0, 0, 0);
      }
    }
    ldsbar();                                   // bar4: buf reads done

    // ---- stage tile t+2 into this buffer (stays in flight) ----
    if (t + 2 < nsb) {
      const int kb2 = kbase + (t + 2) * TK;
      const size_t br2 = (size_t)btab[b * 32 + (kb2 >> 7)] * BS + (kb2 & (BS - 1));
      stage_tile8(&KB[buf][0][0], &KR[buf][0][0], kvn, kvr, br2, w, l);
    }
  }

  // ---- write partials: O (unnormalized, f16), m, l ----
  _Float16* pop = po + (size_t)(b * nc + c) * H_ * DN;
  #pragma unroll
  for (int dt = 0; dt < 8; ++dt)
    #pragma unroll
    for (int r = 0; r < 4; ++r)
      pop[(size_t)(hp * 16 + kd + r) * DN + dq * 128 + dt * 16 + l15] =
          (_Float16)acc[dt][r];
  const int fs = nsb & 1;
  if (tid < H_) {
    const size_t o = ((size_t)(b * nc + c) * H_ + tid) * 2;
    ml[o] = Mrun[fs][tid]; ml[o + 1] = Lrun[fs][tid];
  }
}

// Kernel 2: merge chunk partials per (b,h).
__global__ __launch_bounds__(256) void mla_reduce(
    const _Float16* __restrict__ po, const float* __restrict__ ml,
    const int* __restrict__ kseq, float* __restrict__ out,
    const int nc, const int chunk)
{
  const int bh = blockIdx.x;
  const int b = bh >> 5, h = bh & 31;
  const int klen = kseq[b];
  const int na = min(nc, (klen + chunk - 1) / chunk);
  const int tid = threadIdx.x;

  float M = NEG_INF;
  for (int c = 0; c < na; ++c)
    M = fmaxf(M, ml[((size_t)(b * nc + c) * H_ + h) * 2]);

  float s0 = 0.f, s1 = 0.f, den = 0.f;
  for (int c = 0; c < na; ++c) {
    const size_t o = ((size_t)(b * nc + c) * H_ + h) * 2;
    const float e = exp2f((ml[o] - M) * LOG2E);
    den += ml[o + 1] * e;
    const _Float16* p = po + ((size_t)(b * nc + c) * H_ + h) * DN;
    s0 += (float)p[tid] * e;
    s1 += (float)p[tid + 256] * e;
  }
  const float inv = 1.f / den;
  float* op = out + ((size_t)b * H_ + h) * DN;
  op[tid]       = s0 * inv;
  op[tid + 256] = s1 * inv;
}

extern "C" void kernel_launch(void* const* d_in, const int* in_sizes, int n_in,
                              void* d_out, int out_size, void* d_ws, size_t ws_size,
                              hipStream_t stream) {
  const float* qn  = (const float*)d_in[0];
  const float* qr  = (const float*)d_in[1];
  const float* kvn = (const float*)d_in[2];
  const float* kvr = (const float*)d_in[3];
  const int*  btab = (const int*)d_in[4];
  const int*  kseq = (const int*)d_in[6];
  float* out = (float*)d_out;

  // workspace-adaptive chunk count: nc chunks of 4096/nc keys
  int nc = 16;
  while (nc > 1 &&
         ((size_t)B_ * nc * H_ * DN * sizeof(_Float16) +
          (size_t)B_ * nc * H_ * 2 * sizeof(float)) > ws_size)
    nc >>= 1;
  const int chunk = MAXKV / nc;

  _Float16* po = (_Float16*)d_ws;                          // [B][nc][H][DN] f16
  float* ml = (float*)(po + (size_t)B_ * nc * H_ * DN);    // [B][nc][H][2]  f32

  mla_chunk<<<B_ * nc, 512, 0, stream>>>(qn, qr, kvn, kvr, btab, kseq,
                                         po, ml, nc, chunk);
  mla_reduce<<<B_ * H_, 256, 0, stream>>>(po, ml, kseq, out, nc, chunk);
}